// Round 3
// baseline (293.759 us; speedup 1.0000x reference)
//
#include <hip/hip_runtime.h>

// ---------------------------------------------------------------------------
// Fully-fused KAN-conv MLP: ONE BLOCK = TWO IMAGES, 512 threads (8 waves),
// each 256-thread half processes one image (phases aligned, shared barriers).
// R16 vs R15: duration was pinned at total-VALU-work / VALUBusy(64%).
// Raise VALUBusy by removing per-wave stall chains:
//  - ALL conv weights (V1/V2/V3) copied to LDS once per block -> every lgkm
//    op is in-order DS -> partial lgkmcnt(N) waits instead of the full
//    lgkmcnt(0) drains that SMEM weight loads forced (15x/conv2, 15x/conv3,
//    ~36x/conv1 per wave).
//  - conv1 input features stored parity-swizzled (even cols 0..13, odd cols
//    14..27) -> pool-window ds_read_b128 are stride-1 (was stride-32B =
//    4-way bank conflict, 4.12M conflict cycles).
//  - 2 images/block amortizes weight-LDS: 37.9KB/block, 4 blocks/CU x 8
//    waves = 32 waves/CU exact residency (grid 1024 = 4/CU, no tail).
// Cardinal cubic B-spline: basis_j(x) = B3(u - j), u = 2.5x+5.5 (4 taps).
// ---------------------------------------------------------------------------

typedef _Float16 h2 __attribute__((ext_vector_type(2)));

__device__ __forceinline__ h2 u2h(unsigned int u) {
  union { unsigned int x; h2 h; } v; v.x = u; return v.h;
}
__device__ __forceinline__ unsigned short f2h_bits(float x) {
  union { _Float16 h; unsigned short u; } v; v.h = (_Float16)x; return v.u;
}
__device__ __forceinline__ float h2f(unsigned short u) {
  union { unsigned short u; _Float16 h; } v; v.u = u; return (float)v.h;
}
__device__ __forceinline__ unsigned int pack2h(float a, float b) {
  return (unsigned int)f2h_bits(a) | ((unsigned int)f2h_bits(b) << 16);
}
__device__ __forceinline__ float fdot2(h2 a, h2 b, float c) {
  return __builtin_amdgcn_fdot2(a, b, c, false);
}

// Basis window (8 f16 packed in uint4) + silu, all in registers.
__device__ __forceinline__ void featurize_regs(float v, uint4& bs, float& silu) {
  silu = v / (1.0f + __expf(-v));
  bs.x = 0u; bs.y = 0u; bs.z = 0u; bs.w = 0u;
  float u = fmaf(v, 2.5f, 5.5f);
  if (u >= 0.0f && u < 11.0f) {
    float tf = floorf(u);
    float f = u - tf, f2 = f * f, f3 = f2 * f, om = 1.0f - f;
    const float c6 = 1.0f / 6.0f;
    float w0 = om * om * om * c6;
    float w1 = (3.0f * f3 - 6.0f * f2 + 4.0f) * c6;
    float w2 = (-3.0f * f3 + 3.0f * f2 + 3.0f * f + 1.0f) * c6;
    float w3 = f3 * c6;
    unsigned long long w01 =
        (unsigned long long)f2h_bits(w0) |
        ((unsigned long long)f2h_bits(w1) << 16) |
        ((unsigned long long)f2h_bits(w2) << 32) |
        ((unsigned long long)f2h_bits(w3) << 48);
    int t = (int)tf;                 // 0..10; window starts at slot t-3
    int s = 16 * t - 48;             // bit shift into 128-bit field
    unsigned long long lo, hi;
    if (s >= 0) {
      lo = (s < 64) ? (w01 << s) : 0ull;
      hi = (s == 0) ? 0ull : ((s < 64) ? (w01 >> (64 - s)) : (w01 << (s - 64)));
    } else {
      lo = w01 >> (-s);
      hi = 0ull;
    }
    bs.x = (unsigned int)lo; bs.y = (unsigned int)(lo >> 32);
    bs.z = (unsigned int)hi; bs.w = (unsigned int)(hi >> 32);
  }
}

// conv2 inner accumulation over a compile-time output-channel subset.
// Weights come from LDS (in-order lgkm -> partial waits). Loads per-kx to
// keep VGPR pressure low.
template <int OB, int NO>
__device__ __forceinline__ void conv2_accum(
    const uint4* bas, const unsigned short* slu16,
    const unsigned int* wV2s, const float* wV2b,
    int y0, int x0, float (&acc)[NO]) {
  #pragma unroll 1
  for (int cky = 0; cky < 15; ++cky) {
    int c = cky / 3, ky = cky - c * 3;
    int ba0 = c * 169 + (y0 + ky) * 13 + x0;
    uint4 q00 = bas[ba0], q01 = bas[ba0 + 1], q02 = bas[ba0 + 2];
    float s00 = h2f(slu16[ba0]), s01 = h2f(slu16[ba0 + 1]), s02 = h2f(slu16[ba0 + 2]);
    const uint4* wp4 = (const uint4*)(wV2s + cky * 60);
    const float* bp  = wV2b + cky * 15;
    #pragma unroll
    for (int kx = 0; kx < 3; ++kx) {
      uint4 wq[NO]; float wb[NO];
      #pragma unroll
      for (int j = 0; j < NO; ++j) {
        wq[j] = wp4[kx * 5 + OB + j];
        wb[j] = bp[kx * 5 + OB + j];
      }
      uint4 q = (kx == 0) ? q00 : ((kx == 1) ? q01 : q02);
      float sl = (kx == 0) ? s00 : ((kx == 1) ? s01 : s02);
      h2 a0 = u2h(q.x), a1 = u2h(q.y), a2 = u2h(q.z), a3 = u2h(q.w);
      #pragma unroll
      for (int j = 0; j < NO; ++j) {
        uint4 w = wq[j];
        float a = acc[j];
        a = fdot2(a0, u2h(w.x), a);
        a = fdot2(a1, u2h(w.y), a);
        a = fdot2(a2, u2h(w.z), a);
        a = fdot2(a3, u2h(w.w), a);
        acc[j] = fmaf(sl, wb[j], a);
      }
    }
  }
}

// ---------------- prep: conv weights + W1p4 + padded W2 ---------------------
__global__ __launch_bounds__(256) void k_prep(
    const float* __restrict__ bw1, const float* __restrict__ sw1,
    const float* __restrict__ bw2, const float* __restrict__ sw2,
    const float* __restrict__ bw3, const float* __restrict__ sw3,
    const float* __restrict__ w1, const float* __restrict__ w2,
    unsigned int* __restrict__ V1s, float* __restrict__ V1b,
    unsigned int* __restrict__ V2s, float* __restrict__ V2b,
    unsigned int* __restrict__ V3s, float* __restrict__ V3b,
    unsigned int* __restrict__ W1p4, float* __restrict__ W2p) {
  int t = blockIdx.x * 256 + threadIdx.x;
  if (t < 180) {  // L1: 9 taps x 5 outs x 4 pairs
    int p = t & 3, o = (t >> 2) % 5, in = t / 20;
    V1s[t] = pack2h(sw1[(o * 9 + in) * 8 + 2 * p], sw1[(o * 9 + in) * 8 + 2 * p + 1]);
  }
  if (t < 45)  { int o = t % 5, in = t / 5; V1b[t] = bw1[o * 9 + in]; }
  if (t < 900) { // L2: 45 taps x 5 outs x 4 pairs
    int p = t & 3, o = (t >> 2) % 5, in = t / 20;
    V2s[t] = pack2h(sw2[(o * 45 + in) * 8 + 2 * p], sw2[(o * 45 + in) * 8 + 2 * p + 1]);
  }
  if (t < 225) { int o = t % 5, in = t / 5; V2b[t] = bw2[o * 45 + in]; }
  if (t < 360) { // L3: 45 taps x 2 outs x 4 pairs
    int p = t & 3, o = (t >> 2) & 1, in = t / 8;
    V3s[t] = pack2h(sw3[(o * 45 + in) * 8 + 2 * p], sw3[(o * 45 + in) * 8 + 2 * p + 1]);
  }
  if (t < 90)  { int o = t % 2, in = t / 2; V3b[t] = bw3[o * 45 + in]; }
  if (t < 43008) {  // W1p4[((g*512)+o)*4+j]: j-th k-pair of group g, out o
    int j = t & 3, o = (t >> 2) & 511, g = t >> 11;
    int kp = g * 4 + j;
    W1p4[t] = (o < 500 && kp < 81)
                  ? pack2h(w1[o * 162 + 2 * kp], w1[o * 162 + 2 * kp + 1])
                  : 0u;
  }
  if (t < 5120) {   // W2p[10][512] zero-padded
    int o = t >> 9, k = t & 511;
    W2p[t] = (k < 500) ? w2[o * 500 + k] : 0.0f;
  }
}

// ---------------- the fused kernel: 512 threads = 2 images ------------------
__global__ __launch_bounds__(512, 8) void k_fused(
    const float* __restrict__ x,
    const unsigned int* __restrict__ V1s, const float* __restrict__ V1b,
    const unsigned int* __restrict__ V2s, const float* __restrict__ V2b,
    const unsigned int* __restrict__ V3s, const float* __restrict__ V3b,
    const unsigned int* __restrict__ W1p4, const float* __restrict__ W2p,
    const float* __restrict__ b1, const float* __restrict__ b2,
    float* __restrict__ out) {
  __shared__ uint4 bas[2][845];               // 2 x 13,520 B
  __shared__ unsigned short slu16[2][848];    // 2 x  1,696 B
  __shared__ float red[2][40];                // fc2 cross-wave scratch
  __shared__ __align__(16) unsigned int wV1s[180];
  __shared__ float wV1b[45];
  __shared__ __align__(16) unsigned int wV2s[900];
  __shared__ float wV2b[225];
  __shared__ __align__(16) unsigned int wV3s[360];
  __shared__ float wV3b[90];                  // weights: 7,200 B shared

  const int tid = threadIdx.x;             // 0..511
  const int h   = tid >> 8;                // image half 0/1
  const int t   = tid & 255;               // lane-in-half

  uint4*          bas_h = bas[h];
  unsigned short* slu_h = slu16[h];
  float*          basF  = (float*)bas_h;
  float*          h3f   = basF + 2048;     // h3 (162 f), dead-by-order region
  unsigned int*   hpk   = (unsigned int*)basF + 2560;  // 84 uints
  const int img = blockIdx.x * 2 + h;

  // P0: weights -> LDS (once per block; shared by both halves)
  if (tid < 180) wV1s[tid] = V1s[tid];
  if (tid < 45)  wV1b[tid] = V1b[tid];
  #pragma unroll
  for (int i = tid; i < 900; i += 512) wV2s[i] = V2s[i];
  if (tid < 225) wV2b[tid] = V2b[tid];
  if (tid < 360) wV3s[tid] = V3s[tid];
  if (tid < 90)  wV3b[tid] = V3b[tid];

  // P1: featurize input image (784 px), parity-swizzled columns:
  //   col xx stored at (xx&1)*14 + (xx>>1)  -> conv1 window reads stride-1
  #pragma unroll 1
  for (int l = t; l < 784; l += 256) {
    uint4 bs; float sl;
    featurize_regs(x[img * 784 + l], bs, sl);
    int y = l / 28, xx = l - y * 28;
    int idx = y * 28 + ((xx & 1) ? 14 : 0) + (xx >> 1);
    bas_h[idx] = bs; slu_h[idx] = f2h_bits(sl);
  }
  __syncthreads();   // covers P0 + P1

  // P2: conv1 (1->5) + 2x2 maxpool; 169 outputs, one per lane (t<169)
  float h1v[5];
  if (t < 169) {
    int py = t / 13, px = t % 13;
    int r0 = py * 2;
    float wacc[4][5];
    #pragma unroll
    for (int wi = 0; wi < 4; ++wi)
      #pragma unroll
      for (int o = 0; o < 5; ++o) wacc[wi][o] = 0.0f;
    #pragma unroll
    for (int r = 0; r < 4; ++r) {
      uint4 q[4]; float sl[4];
      #pragma unroll
      for (int c = 0; c < 4; ++c) {
        // swizzled address of col 2*px+c: (c&1)*14 + px + (c>>1)
        int idx = (r0 + r) * 28 + ((c & 1) ? 14 : 0) + px + (c >> 1);
        q[c]  = bas_h[idx];
        sl[c] = h2f(slu_h[idx]);
      }
      #pragma unroll
      for (int c = 0; c < 4; ++c) {
        h2 a0 = u2h(q[c].x), a1 = u2h(q[c].y), a2 = u2h(q[c].z), a3 = u2h(q[c].w);
        #pragma unroll
        for (int dy = 0; dy < 2; ++dy) {
          #pragma unroll
          for (int dx = 0; dx < 2; ++dx) {
            int ky = r - dy, kx = c - dx;
            if (ky >= 0 && ky < 3 && kx >= 0 && kx < 3) {
              const uint4* wp4 = (const uint4*)(wV1s + (ky * 3 + kx) * 20);
              const float* bp  = wV1b + (ky * 3 + kx) * 5;
              #pragma unroll
              for (int o = 0; o < 5; ++o) {
                uint4 w = wp4[o];
                float acc = wacc[dy * 2 + dx][o];
                acc = fdot2(a0, u2h(w.x), acc);
                acc = fdot2(a1, u2h(w.y), acc);
                acc = fdot2(a2, u2h(w.z), acc);
                acc = fdot2(a3, u2h(w.w), acc);
                wacc[dy * 2 + dx][o] = fmaf(sl[c], bp[o], acc);
              }
            }
          }
        }
      }
    }
    #pragma unroll
    for (int o = 0; o < 5; ++o)
      h1v[o] = fmaxf(fmaxf(wacc[0][o], wacc[1][o]),
                     fmaxf(wacc[2][o], wacc[3][o]));
  }
  __syncthreads();  // all conv1 LDS reads done
  // write featurized h1 (aliases the input-pixel region; plain layout)
  if (t < 169) {
    #pragma unroll
    for (int o = 0; o < 5; ++o) {
      uint4 bs; float sl;
      featurize_regs(h1v[o], bs, sl);
      bas_h[o * 169 + t] = bs; slu_h[o * 169 + t] = f2h_bits(sl);
    }
  }
  __syncthreads();

  // P4: conv2 (5->5); lanes split by (position, channel-group):
  //   og=0 (waves 0,1 of half): ch 0..2   og=1 (waves 2,3): ch 3..4
  int og = __builtin_amdgcn_readfirstlane(t >> 7);   // wave-uniform
  int p2 = t & 127;
  float acc2a[3] = {0.0f, 0.0f, 0.0f};
  float acc2b[2] = {0.0f, 0.0f};
  {
    int pc = (p2 < 121) ? p2 : 120;     // clamp (writeback guarded)
    int y0 = pc / 11, x0 = pc % 11;
    if (og == 0) conv2_accum<0, 3>(bas_h, slu_h, wV2s, wV2b, y0, x0, acc2a);
    else         conv2_accum<3, 2>(bas_h, slu_h, wV2s, wV2b, y0, x0, acc2b);
  }
  __syncthreads();  // all conv2 reads done before h2 overwrites bas
  if (p2 < 121) {
    if (og == 0) {
      #pragma unroll
      for (int j = 0; j < 3; ++j) {
        uint4 bs; float sl;
        featurize_regs(acc2a[j], bs, sl);
        bas_h[j * 121 + p2] = bs; slu_h[j * 121 + p2] = f2h_bits(sl);
      }
    } else {
      #pragma unroll
      for (int j = 0; j < 2; ++j) {
        uint4 bs; float sl;
        featurize_regs(acc2b[j], bs, sl);
        bas_h[(3 + j) * 121 + p2] = bs; slu_h[(3 + j) * 121 + p2] = f2h_bits(sl);
      }
    }
  }
  __syncthreads();

  // P6: conv3 (5->2); lanes split by (position, output):
  //   waves 0,1 of half: out 0   waves 2,3: out 1
  float acc3 = 0.0f;
  {
    int ou = og;                         // wave-uniform
    int pc = (p2 < 81) ? p2 : 80;
    int y0 = pc / 9, x0 = pc % 9;
    #pragma unroll 1
    for (int cky = 0; cky < 15; ++cky) {
      int c = cky / 3, ky = cky - c * 3;
      int ba0 = c * 121 + (y0 + ky) * 11 + x0;
      uint4 q00 = bas_h[ba0], q01 = bas_h[ba0 + 1], q02 = bas_h[ba0 + 2];
      float s00 = h2f(slu_h[ba0]), s01 = h2f(slu_h[ba0 + 1]), s02 = h2f(slu_h[ba0 + 2]);
      const uint4* wp4 = (const uint4*)(wV3s + cky * 24);
      const float* bp  = wV3b + cky * 6;
      #pragma unroll
      for (int kx = 0; kx < 3; ++kx) {
        uint4 w = wp4[kx * 2 + ou];
        float wb = bp[kx * 2 + ou];
        uint4 q = (kx == 0) ? q00 : ((kx == 1) ? q01 : q02);
        float sl = (kx == 0) ? s00 : ((kx == 1) ? s01 : s02);
        h2 a0 = u2h(q.x), a1 = u2h(q.y), a2 = u2h(q.z), a3 = u2h(q.w);
        float a = acc3;
        a = fdot2(a0, u2h(w.x), a);
        a = fdot2(a1, u2h(w.y), a);
        a = fdot2(a2, u2h(w.z), a);
        a = fdot2(a3, u2h(w.w), a);
        acc3 = fmaf(sl, wb, a);
      }
    }
  }
  __syncthreads();  // all conv3 reads done before h3 overwrites bas region
  if (p2 < 81) h3f[og * 81 + p2] = acc3;
  __syncthreads();
  if (t < 84)
    hpk[t] = (t < 81) ? pack2h(h3f[2 * t], h3f[2 * t + 1]) : 0u;
  __syncthreads();

  // P7: fc1 (162->500) + bias + ReLU; 2 outs/lane; double-buffered global
  // loads (vmcnt is in-order & separate from LDS lgkmcnt -> real prefetch).
  float fa[2] = {0.0f, 0.0f};
  {
    const uint4* hp4 = (const uint4*)hpk;
    const uint4* wbase = (const uint4*)W1p4 + t;
    uint4 wA[2], wB[2];
    #pragma unroll
    for (int i = 0; i < 2; ++i) wA[i] = wbase[i * 256];   // group 0
    #pragma unroll 1
    for (int g = 0; g < 21; g += 2) {
      if (g + 1 < 21) {
        const uint4* p = wbase + (g + 1) * 512;
        #pragma unroll
        for (int i = 0; i < 2; ++i) wB[i] = p[i * 256];
      }
      {
        uint4 hk = hp4[g];
        #pragma unroll
        for (int i = 0; i < 2; ++i) {
          float a = fa[i];
          a = fdot2(u2h(hk.x), u2h(wA[i].x), a);
          a = fdot2(u2h(hk.y), u2h(wA[i].y), a);
          a = fdot2(u2h(hk.z), u2h(wA[i].z), a);
          a = fdot2(u2h(hk.w), u2h(wA[i].w), a);
          fa[i] = a;
        }
      }
      if (g + 2 < 21) {
        const uint4* p = wbase + (g + 2) * 512;
        #pragma unroll
        for (int i = 0; i < 2; ++i) wA[i] = p[i * 256];
      }
      if (g + 1 < 21) {
        uint4 hk = hp4[g + 1];
        #pragma unroll
        for (int i = 0; i < 2; ++i) {
          float a = fa[i];
          a = fdot2(u2h(hk.x), u2h(wB[i].x), a);
          a = fdot2(u2h(hk.y), u2h(wB[i].y), a);
          a = fdot2(u2h(hk.z), u2h(wB[i].z), a);
          a = fdot2(u2h(hk.w), u2h(wB[i].w), a);
          fa[i] = a;
        }
      }
    }
  }
  #pragma unroll
  for (int i = 0; i < 2; ++i) {
    int o = t + 256 * i;
    float bb = (o < 500) ? b1[o] : 0.0f;
    float v = fa[i] + bb;
    basF[o] = (v > 0.0f && o < 500) ? v : 0.0f;  // fc1out[512] in bas[0..127]
  }
  __syncthreads();

  // P8: fc2 (500->10): lane covers k = 2*t..2*t+1, shfl + LDS reduction
  float acc10[10];
  {
    float2 ha = ((const float2*)basF)[t];
    #pragma unroll
    for (int o = 0; o < 10; ++o) {
      float2 w = ((const float2*)&W2p[o * 512])[t];
      acc10[o] = ha.x * w.x + ha.y * w.y;
    }
  }
  #pragma unroll
  for (int off = 32; off > 0; off >>= 1) {
    #pragma unroll
    for (int o = 0; o < 10; ++o) acc10[o] += __shfl_down(acc10[o], off);
  }
  if ((t & 63) == 0) {
    int wid = t >> 6;
    #pragma unroll
    for (int o = 0; o < 10; ++o) red[h][wid * 10 + o] = acc10[o];
  }
  __syncthreads();
  if (t < 10)
    out[img * 10 + t] =
        red[h][t] + red[h][10 + t] + red[h][20 + t] + red[h][30 + t] + b2[t];
}

// ---------------------------------------------------------------------------
extern "C" void kernel_launch(void* const* d_in, const int* in_sizes, int n_in,
                              void* d_out, int out_size, void* d_ws, size_t ws_size,
                              hipStream_t stream) {
  (void)in_sizes; (void)n_in; (void)out_size; (void)ws_size;
  const float* x   = (const float*)d_in[0];
  const float* bw1 = (const float*)d_in[1];
  const float* sw1 = (const float*)d_in[2];
  const float* bw2 = (const float*)d_in[3];
  const float* sw2 = (const float*)d_in[4];
  const float* bw3 = (const float*)d_in[5];
  const float* sw3 = (const float*)d_in[6];
  const float* w1  = (const float*)d_in[7];
  const float* b1  = (const float*)d_in[8];
  const float* w2  = (const float*)d_in[9];
  const float* b2  = (const float*)d_in[10];
  float* out = (float*)d_out;

  char* ws = (char*)d_ws;
  unsigned int* V1s  = (unsigned int*)(ws);           // 180 u   (720 B)
  float*        V1b  = (float*)(ws + 768);            // 45 f    (180 B)
  unsigned int* V2s  = (unsigned int*)(ws + 1024);    // 900 u   (3,600 B)
  float*        V2b  = (float*)(ws + 4672);           // 225 f   (900 B)
  unsigned int* V3s  = (unsigned int*)(ws + 5632);    // 360 u   (1,440 B)
  float*        V3b  = (float*)(ws + 7168);           // 90 f    (360 B)
  float*        W2p  = (float*)(ws + 7680);           // 5,120 f (20,480 B)
  unsigned int* W1p4 = (unsigned int*)(ws + 28672);   // 43,008 u (172,032 B)

  k_prep<<<168, 256, 0, stream>>>(bw1, sw1, bw2, sw2, bw3, sw3, w1, w2,
                                  V1s, V1b, V2s, V2b, V3s, V3b, W1p4, W2p);
  k_fused<<<1024, 512, 0, stream>>>(x, V1s, V1b, V2s, V2b, V3s, V3b,
                                    W1p4, W2p, b1, b2, out);
}

// Round 4
// 140.397 us; speedup vs baseline: 2.0924x; 2.0924x over previous
//
#include <hip/hip_runtime.h>

// ---------------------------------------------------------------------------
// Fully-fused KAN-conv MLP: ONE BLOCK = ONE IMAGE, FOUR WAVES (R15 structure).
// R17 vs R15/R16:
//  - R16 regression root-caused: weights-in-LDS forced weights through VGPRs
//    under a hard register cap -> 630 MB scratch spill traffic. REVERTED:
//    weights stay in global, wave-uniform -> s_load -> SGPR operands (free).
//  - R15 plateau root-caused: at VGPR=32 the allocator serializes the per-cky
//    LDS record reads (~120cy each, drained with the SMEM weight loads).
//    Fix: hand-written one-iteration-ahead prefetch of LDS records (conv1
//    row-ahead, conv2/conv3 cky-ahead) forces ~55-60 live VGPRs of real
//    pipelining, still under the 64-VGPR cap of launch_bounds(256,8).
//  - Weights repacked per wave-group (og) so each cky's scalar weight row is
//    CONTIGUOUS -> 2-3 s_load_dwordx16 instead of strided gathers.
// Cardinal cubic B-spline: basis_j(x) = B3(u - j), u = 2.5x+5.5 (4 taps).
// ---------------------------------------------------------------------------

typedef _Float16 h2 __attribute__((ext_vector_type(2)));

__device__ __forceinline__ h2 u2h(unsigned int u) {
  union { unsigned int x; h2 h; } v; v.x = u; return v.h;
}
__device__ __forceinline__ unsigned short f2h_bits(float x) {
  union { _Float16 h; unsigned short u; } v; v.h = (_Float16)x; return v.u;
}
__device__ __forceinline__ float h2f(unsigned short u) {
  union { unsigned short u; _Float16 h; } v; v.u = u; return (float)v.h;
}
__device__ __forceinline__ unsigned int pack2h(float a, float b) {
  return (unsigned int)f2h_bits(a) | ((unsigned int)f2h_bits(b) << 16);
}
__device__ __forceinline__ float fdot2(h2 a, h2 b, float c) {
  return __builtin_amdgcn_fdot2(a, b, c, false);
}

// Basis window (8 f16 packed in uint4) + silu, all in registers.
__device__ __forceinline__ void featurize_regs(float v, uint4& bs, float& silu) {
  silu = v / (1.0f + __expf(-v));
  bs.x = 0u; bs.y = 0u; bs.z = 0u; bs.w = 0u;
  float u = fmaf(v, 2.5f, 5.5f);
  if (u >= 0.0f && u < 11.0f) {
    float tf = floorf(u);
    float f = u - tf, f2 = f * f, f3 = f2 * f, om = 1.0f - f;
    const float c6 = 1.0f / 6.0f;
    float w0 = om * om * om * c6;
    float w1 = (3.0f * f3 - 6.0f * f2 + 4.0f) * c6;
    float w2 = (-3.0f * f3 + 3.0f * f2 + 3.0f * f + 1.0f) * c6;
    float w3 = f3 * c6;
    unsigned long long w01 =
        (unsigned long long)f2h_bits(w0) |
        ((unsigned long long)f2h_bits(w1) << 16) |
        ((unsigned long long)f2h_bits(w2) << 32) |
        ((unsigned long long)f2h_bits(w3) << 48);
    int t = (int)tf;                 // 0..10; window starts at slot t-3
    int s = 16 * t - 48;             // bit shift into 128-bit field
    unsigned long long lo, hi;
    if (s >= 0) {
      lo = (s < 64) ? (w01 << s) : 0ull;
      hi = (s == 0) ? 0ull : ((s < 64) ? (w01 >> (64 - s)) : (w01 << (s - 64)));
    } else {
      lo = w01 >> (-s);
      hi = 0ull;
    }
    bs.x = (unsigned int)lo; bs.y = (unsigned int)(lo >> 32);
    bs.z = (unsigned int)hi; bs.w = (unsigned int)(hi >> 32);
  }
}

// KAN 3x3-conv accumulation, one position per lane, NO output channels,
// with one-cky-ahead prefetch of the LDS records. Weights (wS/wB) are
// og-contiguous global arrays -> wide s_loads -> SGPR operands.
// CHS = channel stride (els), ROWW = row width of input feature map.
template <int NO, int CHS, int ROWW>
__device__ __forceinline__ void kconv_accum(
    const uint4* bas, const unsigned short* slu,
    const uint4* __restrict__ wS, const float* __restrict__ wB,
    int y0, int x0, float (&acc)[NO]) {
  uint4 q0, q1, q2; unsigned short s0, s1, s2;
  {
    int ba = y0 * ROWW + x0;              // cky = 0: c=0, ky=0
    q0 = bas[ba]; q1 = bas[ba + 1]; q2 = bas[ba + 2];
    s0 = slu[ba]; s1 = slu[ba + 1]; s2 = slu[ba + 2];
  }
  #pragma unroll 1
  for (int cky = 0; cky < 15; ++cky) {
    uint4 n0 = {0, 0, 0, 0}, n1 = {0, 0, 0, 0}, n2 = {0, 0, 0, 0};
    unsigned short t0 = 0, t1 = 0, t2 = 0;
    if (cky < 14) {                       // prefetch next cky's records
      int ck1 = cky + 1;
      int c = ck1 / 3, ky = ck1 - c * 3;
      int ba = c * CHS + (y0 + ky) * ROWW + x0;
      n0 = bas[ba]; n1 = bas[ba + 1]; n2 = bas[ba + 2];
      t0 = slu[ba]; t1 = slu[ba + 1]; t2 = slu[ba + 2];
    }
    const uint4* wp = wS + cky * (3 * NO);
    const float* bp = wB + cky * (3 * NO);
    #pragma unroll
    for (int kx = 0; kx < 3; ++kx) {
      uint4 q = (kx == 0) ? q0 : ((kx == 1) ? q1 : q2);
      float sl = h2f((kx == 0) ? s0 : ((kx == 1) ? s1 : s2));
      h2 a0 = u2h(q.x), a1 = u2h(q.y), a2 = u2h(q.z), a3 = u2h(q.w);
      #pragma unroll
      for (int j = 0; j < NO; ++j) {
        uint4 w = wp[kx * NO + j];
        float a = acc[j];
        a = fdot2(a0, u2h(w.x), a);
        a = fdot2(a1, u2h(w.y), a);
        a = fdot2(a2, u2h(w.z), a);
        a = fdot2(a3, u2h(w.w), a);
        acc[j] = fmaf(sl, bp[kx * NO + j], a);
      }
    }
    q0 = n0; q1 = n1; q2 = n2; s0 = t0; s1 = t1; s2 = t2;
  }
}

// ---------------- prep: conv weights (og-packed) + W1p4 + padded W2 ---------
__global__ __launch_bounds__(256) void k_prep(
    const float* __restrict__ bw1, const float* __restrict__ sw1,
    const float* __restrict__ bw2, const float* __restrict__ sw2,
    const float* __restrict__ bw3, const float* __restrict__ sw3,
    const float* __restrict__ w1, const float* __restrict__ w2,
    unsigned int* __restrict__ V1s, float* __restrict__ V1b,
    unsigned int* __restrict__ V2G0s, float* __restrict__ V2G0b,
    unsigned int* __restrict__ V2G1s, float* __restrict__ V2G1b,
    unsigned int* __restrict__ V3Gs, float* __restrict__ V3Gb,
    unsigned int* __restrict__ W1p4, float* __restrict__ W2p) {
  int t = blockIdx.x * 256 + threadIdx.x;
  if (t < 180) {  // L1: 9 taps x 5 outs x 4 pairs (tap-major, o contiguous)
    int p = t & 3, o = (t >> 2) % 5, in = t / 20;
    V1s[t] = pack2h(sw1[(o * 9 + in) * 8 + 2 * p], sw1[(o * 9 + in) * 8 + 2 * p + 1]);
  }
  if (t < 45)  { int o = t % 5, in = t / 5; V1b[t] = bw1[o * 9 + in]; }
  // L2 og0 (ch 0..2): [cky][kx][j<3] uint4 -> 540 words
  if (t < 540) {
    int p = t & 3, u4 = t >> 2;
    int j = u4 % 3, kx = (u4 / 3) % 3, cky = u4 / 9;
    int in = (cky / 3) * 9 + (cky % 3) * 3 + kx;
    V2G0s[t] = pack2h(sw2[(j * 45 + in) * 8 + 2 * p], sw2[(j * 45 + in) * 8 + 2 * p + 1]);
  }
  if (t < 135) {  // og0 biases
    int j = t % 3, kx = (t / 3) % 3, cky = t / 9;
    int in = (cky / 3) * 9 + (cky % 3) * 3 + kx;
    V2G0b[t] = bw2[j * 45 + in];
  }
  // L2 og1 (ch 3..4): [cky][kx][j<2] uint4 -> 360 words
  if (t < 360) {
    int p = t & 3, u4 = t >> 2;
    int j = u4 % 2, kx = (u4 / 2) % 3, cky = u4 / 6;
    int o = 3 + j;
    int in = (cky / 3) * 9 + (cky % 3) * 3 + kx;
    V2G1s[t] = pack2h(sw2[(o * 45 + in) * 8 + 2 * p], sw2[(o * 45 + in) * 8 + 2 * p + 1]);
  }
  if (t < 90) {   // og1 biases
    int j = t % 2, kx = (t / 2) % 3, cky = t / 6;
    int o = 3 + j;
    int in = (cky / 3) * 9 + (cky % 3) * 3 + kx;
    V2G1b[t] = bw2[o * 45 + in];
  }
  // L3: [ou][cky][kx] uint4 -> 360 words
  if (t < 360) {
    int p = t & 3, u4 = t >> 2;
    int kx = u4 % 3, cky = (u4 / 3) % 15, ou = u4 / 45;
    int in = (cky / 3) * 9 + (cky % 3) * 3 + kx;
    V3Gs[t] = pack2h(sw3[(ou * 45 + in) * 8 + 2 * p], sw3[(ou * 45 + in) * 8 + 2 * p + 1]);
  }
  if (t < 90) {
    int kx = t % 3, cky = (t / 3) % 15, ou = t / 45;
    int in = (cky / 3) * 9 + (cky % 3) * 3 + kx;
    V3Gb[t] = bw3[ou * 45 + in];
  }
  if (t < 43008) {  // W1p4[((g*512)+o)*4+j]: j-th k-pair of group g, out o
    int j = t & 3, o = (t >> 2) & 511, g = t >> 11;
    int kp = g * 4 + j;
    W1p4[t] = (o < 500 && kp < 81)
                  ? pack2h(w1[o * 162 + 2 * kp], w1[o * 162 + 2 * kp + 1])
                  : 0u;
  }
  if (t < 5120) {   // W2p[10][512] zero-padded
    int o = t >> 9, k = t & 511;
    W2p[t] = (k < 500) ? w2[o * 500 + k] : 0.0f;
  }
}

// ---------------- the fused per-image kernel (four waves per block) ---------
__global__ __launch_bounds__(256, 8) void k_fused(
    const float* __restrict__ x,
    const unsigned int* __restrict__ V1s, const float* __restrict__ V1b,
    const unsigned int* __restrict__ V2G0s, const float* __restrict__ V2G0b,
    const unsigned int* __restrict__ V2G1s, const float* __restrict__ V2G1b,
    const unsigned int* __restrict__ V3Gs, const float* __restrict__ V3Gb,
    const unsigned int* __restrict__ W1p4, const float* __restrict__ W2p,
    const float* __restrict__ b1, const float* __restrict__ b2,
    float* __restrict__ out) {
  __shared__ uint4 bas[845];               // 13,520 B
  __shared__ unsigned short slu16[848];    //  1,696 B
  __shared__ float red[40];                // fc2 cross-wave scratch
  float*        basF = (float*)bas;        // dword view of bas
  float*        h3f  = basF + 2048;        // h3 (162 f), dead-by-order region
  unsigned int* hpk  = (unsigned int*)basF + 2560;  // 84 uints
  const int b = blockIdx.x;
  const int tid = threadIdx.x;             // 0..255, four waves

  // P1: featurize input image (784 px)
  #pragma unroll 1
  for (int l = tid; l < 784; l += 256) {
    uint4 bs; float sl;
    featurize_regs(x[b * 784 + l], bs, sl);
    bas[l] = bs; slu16[l] = f2h_bits(sl);
  }
  __syncthreads();

  // P2: conv1 (1->5) + 2x2 maxpool; one pooled output per lane (tid<169),
  // with one-row-ahead prefetch of the 4x4 pool window.
  float h1v[5];
  if (tid < 169) {
    int py = tid / 13, px = tid % 13;
    int r0 = py * 2, c0 = px * 2;
    float wacc[4][5];
    #pragma unroll
    for (int wi = 0; wi < 4; ++wi)
      #pragma unroll
      for (int o = 0; o < 5; ++o) wacc[wi][o] = 0.0f;
    uint4 q[4]; unsigned short su[4];
    {
      int ba = r0 * 28 + c0;
      #pragma unroll
      for (int c = 0; c < 4; ++c) { q[c] = bas[ba + c]; su[c] = slu16[ba + c]; }
    }
    #pragma unroll
    for (int r = 0; r < 4; ++r) {
      uint4 nq[4]; unsigned short ns[4];
      if (r < 3) {
        int ba = (r0 + r + 1) * 28 + c0;
        #pragma unroll
        for (int c = 0; c < 4; ++c) { nq[c] = bas[ba + c]; ns[c] = slu16[ba + c]; }
      }
      #pragma unroll
      for (int c = 0; c < 4; ++c) {
        h2 a0 = u2h(q[c].x), a1 = u2h(q[c].y), a2 = u2h(q[c].z), a3 = u2h(q[c].w);
        float sl = h2f(su[c]);
        #pragma unroll
        for (int dy = 0; dy < 2; ++dy) {
          #pragma unroll
          for (int dx = 0; dx < 2; ++dx) {
            int ky = r - dy, kx = c - dx;
            if (ky >= 0 && ky < 3 && kx >= 0 && kx < 3) {
              const unsigned int* wp = V1s + (ky * 3 + kx) * 20;
              const float* bp = V1b + (ky * 3 + kx) * 5;
              #pragma unroll
              for (int o = 0; o < 5; ++o) {
                float acc = wacc[dy * 2 + dx][o];
                acc = fdot2(a0, u2h(wp[o * 4 + 0]), acc);
                acc = fdot2(a1, u2h(wp[o * 4 + 1]), acc);
                acc = fdot2(a2, u2h(wp[o * 4 + 2]), acc);
                acc = fdot2(a3, u2h(wp[o * 4 + 3]), acc);
                wacc[dy * 2 + dx][o] = fmaf(sl, bp[o], acc);
              }
            }
          }
        }
      }
      if (r < 3) {
        #pragma unroll
        for (int c = 0; c < 4; ++c) { q[c] = nq[c]; su[c] = ns[c]; }
      }
    }
    #pragma unroll
    for (int o = 0; o < 5; ++o)
      h1v[o] = fmaxf(fmaxf(wacc[0][o], wacc[1][o]),
                     fmaxf(wacc[2][o], wacc[3][o]));
  }
  __syncthreads();  // all conv1 LDS reads (all waves) done
  // write featurized h1 (aliases the input-pixel region)
  if (tid < 169) {
    #pragma unroll
    for (int o = 0; o < 5; ++o) {
      uint4 bs; float sl;
      featurize_regs(h1v[o], bs, sl);
      bas[o * 169 + tid] = bs; slu16[o * 169 + tid] = f2h_bits(sl);
    }
  }
  __syncthreads();

  // P4: conv2 (5->5); lanes split by (position, channel-group):
  //   og=0 (waves 0,1): channels 0..2   og=1 (waves 2,3): channels 3..4
  int og = __builtin_amdgcn_readfirstlane(tid >> 7);   // wave-uniform
  int p2 = tid & 127;
  float acc2a[3] = {0.0f, 0.0f, 0.0f};
  float acc2b[2] = {0.0f, 0.0f};
  {
    int pc = (p2 < 121) ? p2 : 120;     // clamp (writeback guarded)
    int y0 = pc / 11, x0 = pc % 11;
    if (og == 0)
      kconv_accum<3, 169, 13>(bas, slu16, (const uint4*)V2G0s, V2G0b, y0, x0, acc2a);
    else
      kconv_accum<2, 169, 13>(bas, slu16, (const uint4*)V2G1s, V2G1b, y0, x0, acc2b);
  }
  __syncthreads();  // all conv2 reads done before h2 overwrites bas
  if (p2 < 121) {
    if (og == 0) {
      #pragma unroll
      for (int j = 0; j < 3; ++j) {
        uint4 bs; float sl;
        featurize_regs(acc2a[j], bs, sl);
        bas[j * 121 + p2] = bs; slu16[j * 121 + p2] = f2h_bits(sl);
      }
    } else {
      #pragma unroll
      for (int j = 0; j < 2; ++j) {
        uint4 bs; float sl;
        featurize_regs(acc2b[j], bs, sl);
        bas[(3 + j) * 121 + p2] = bs; slu16[(3 + j) * 121 + p2] = f2h_bits(sl);
      }
    }
  }
  __syncthreads();

  // P6: conv3 (5->2); lanes split by (position, output):
  //   waves 0,1: out 0   waves 2,3: out 1
  float acc3[1] = {0.0f};
  {
    int pc = (p2 < 81) ? p2 : 80;
    int y0 = pc / 9, x0 = pc % 9;
    kconv_accum<1, 121, 11>(bas, slu16, (const uint4*)V3Gs + og * 45,
                            V3Gb + og * 45, y0, x0, acc3);
  }
  __syncthreads();  // all conv3 reads done before h3 overwrites bas region
  if (p2 < 81) h3f[og * 81 + p2] = acc3[0];
  __syncthreads();
  if (tid < 84)
    hpk[tid] = (tid < 81) ? pack2h(h3f[2 * tid], h3f[2 * tid + 1]) : 0u;
  __syncthreads();

  // P7: fc1 (162->500) + bias + ReLU; 2 outs/lane; double-buffered global
  // loads (vmcnt is in-order & separate from LDS lgkmcnt -> real prefetch).
  float fa[2] = {0.0f, 0.0f};
  {
    const uint4* hp4 = (const uint4*)hpk;
    const uint4* wbase = (const uint4*)W1p4 + tid;
    uint4 wA[2], wB[2];
    #pragma unroll
    for (int i = 0; i < 2; ++i) wA[i] = wbase[i * 256];   // group 0
    #pragma unroll 1
    for (int g = 0; g < 21; g += 2) {
      if (g + 1 < 21) {
        const uint4* p = wbase + (g + 1) * 512;
        #pragma unroll
        for (int i = 0; i < 2; ++i) wB[i] = p[i * 256];
      }
      {
        uint4 hk = hp4[g];
        #pragma unroll
        for (int i = 0; i < 2; ++i) {
          float a = fa[i];
          a = fdot2(u2h(hk.x), u2h(wA[i].x), a);
          a = fdot2(u2h(hk.y), u2h(wA[i].y), a);
          a = fdot2(u2h(hk.z), u2h(wA[i].z), a);
          a = fdot2(u2h(hk.w), u2h(wA[i].w), a);
          fa[i] = a;
        }
      }
      if (g + 2 < 21) {
        const uint4* p = wbase + (g + 2) * 512;
        #pragma unroll
        for (int i = 0; i < 2; ++i) wA[i] = p[i * 256];
      }
      if (g + 1 < 21) {
        uint4 hk = hp4[g + 1];
        #pragma unroll
        for (int i = 0; i < 2; ++i) {
          float a = fa[i];
          a = fdot2(u2h(hk.x), u2h(wB[i].x), a);
          a = fdot2(u2h(hk.y), u2h(wB[i].y), a);
          a = fdot2(u2h(hk.z), u2h(wB[i].z), a);
          a = fdot2(u2h(hk.w), u2h(wB[i].w), a);
          fa[i] = a;
        }
      }
    }
  }
  #pragma unroll
  for (int i = 0; i < 2; ++i) {
    int o = tid + 256 * i;
    float bb = (o < 500) ? b1[o] : 0.0f;
    float v = fa[i] + bb;
    basF[o] = (v > 0.0f && o < 500) ? v : 0.0f;  // fc1out[512] in bas[0..127]
  }
  __syncthreads();

  // P8: fc2 (500->10): lane covers k = 2*tid..2*tid+1, shfl + LDS reduction
  float acc10[10];
  {
    float2 ha = ((const float2*)basF)[tid];
    #pragma unroll
    for (int o = 0; o < 10; ++o) {
      float2 w = ((const float2*)&W2p[o * 512])[tid];
      acc10[o] = ha.x * w.x + ha.y * w.y;
    }
  }
  #pragma unroll
  for (int off = 32; off > 0; off >>= 1) {
    #pragma unroll
    for (int o = 0; o < 10; ++o) acc10[o] += __shfl_down(acc10[o], off);
  }
  if ((tid & 63) == 0) {
    int wid = tid >> 6;
    #pragma unroll
    for (int o = 0; o < 10; ++o) red[wid * 10 + o] = acc10[o];
  }
  __syncthreads();
  if (tid < 10)
    out[b * 10 + tid] = red[tid] + red[10 + tid] + red[20 + tid] + red[30 + tid] + b2[tid];
}

// ---------------------------------------------------------------------------
extern "C" void kernel_launch(void* const* d_in, const int* in_sizes, int n_in,
                              void* d_out, int out_size, void* d_ws, size_t ws_size,
                              hipStream_t stream) {
  (void)in_sizes; (void)n_in; (void)out_size; (void)ws_size;
  const float* x   = (const float*)d_in[0];
  const float* bw1 = (const float*)d_in[1];
  const float* sw1 = (const float*)d_in[2];
  const float* bw2 = (const float*)d_in[3];
  const float* sw2 = (const float*)d_in[4];
  const float* bw3 = (const float*)d_in[5];
  const float* sw3 = (const float*)d_in[6];
  const float* w1  = (const float*)d_in[7];
  const float* b1  = (const float*)d_in[8];
  const float* w2  = (const float*)d_in[9];
  const float* b2  = (const float*)d_in[10];
  float* out = (float*)d_out;

  char* ws = (char*)d_ws;
  unsigned int* V1s   = (unsigned int*)(ws);           // 180 u   (720 B)
  float*        V1b   = (float*)(ws + 768);            // 45 f    (180 B)
  unsigned int* V2G0s = (unsigned int*)(ws + 1024);    // 540 u   (2,160 B)
  unsigned int* V2G1s = (unsigned int*)(ws + 3200);    // 360 u   (1,440 B)
  unsigned int* V3Gs  = (unsigned int*)(ws + 4640);    // 360 u   (1,440 B)
  float*        V2G0b = (float*)(ws + 6080);           // 135 f   (540 B)
  float*        V2G1b = (float*)(ws + 6624);           // 90 f    (360 B)
  float*        V3Gb  = (float*)(ws + 6984);           // 90 f    (360 B)
  float*        W2p   = (float*)(ws + 7680);           // 5,120 f (20,480 B)
  unsigned int* W1p4  = (unsigned int*)(ws + 28672);   // 43,008 u (172,032 B)

  k_prep<<<168, 256, 0, stream>>>(bw1, sw1, bw2, sw2, bw3, sw3, w1, w2,
                                  V1s, V1b, V2G0s, V2G0b, V2G1s, V2G1b,
                                  V3Gs, V3Gb, W1p4, W2p);
  k_fused<<<2048, 256, 0, stream>>>(x, V1s, V1b, V2G0s, V2G0b, V2G1s, V2G1b,
                                    V3Gs, V3Gb, W1p4, W2p, b1, b2, out);
}

// Round 5
// 128.173 us; speedup vs baseline: 2.2919x; 1.0954x over previous
//
#include <hip/hip_runtime.h>

// ---------------------------------------------------------------------------
// Fully-fused KAN-conv MLP: ONE BLOCK = ONE IMAGE, FOUR WAVES (R15 structure).
// R18 = R15 base + stall-structure fixes (R17's prefetch REVERTED — compiler
// sank the prefetch loads back to use sites and kept VGPR=32; only overhead
// remained):
//  - conv1 TAP-OUTER: per (ky,kx) tap: ONE contiguous 25-dword SMEM weight
//    row load + 8 LDS reads at loop top, then 100 straight VALU ops.
//    9 lgkm drains/lane instead of ~36 interior mid-math drains.
//  - conv2/conv3: og-contiguous weight arrays (R17 packing) + plain c-outer/
//    ky-inner loops with incremental addressing (no cky/3 magic-muls).
//  - weights stay in GLOBAL (wave-uniform -> s_load -> SGPR operands, zero
//    VGPR cost). R16 proved weights-in-LDS spills catastrophically.
// Cardinal cubic B-spline: basis_j(x) = B3(u - j), u = 2.5x+5.5 (4 taps).
// ---------------------------------------------------------------------------

typedef _Float16 h2 __attribute__((ext_vector_type(2)));

__device__ __forceinline__ h2 u2h(unsigned int u) {
  union { unsigned int x; h2 h; } v; v.x = u; return v.h;
}
__device__ __forceinline__ unsigned short f2h_bits(float x) {
  union { _Float16 h; unsigned short u; } v; v.h = (_Float16)x; return v.u;
}
__device__ __forceinline__ float h2f(unsigned short u) {
  union { unsigned short u; _Float16 h; } v; v.u = u; return (float)v.h;
}
__device__ __forceinline__ unsigned int pack2h(float a, float b) {
  return (unsigned int)f2h_bits(a) | ((unsigned int)f2h_bits(b) << 16);
}
__device__ __forceinline__ float fdot2(h2 a, h2 b, float c) {
  return __builtin_amdgcn_fdot2(a, b, c, false);
}

// Basis window (8 f16 packed in uint4) + silu, all in registers.
__device__ __forceinline__ void featurize_regs(float v, uint4& bs, float& silu) {
  silu = v / (1.0f + __expf(-v));
  bs.x = 0u; bs.y = 0u; bs.z = 0u; bs.w = 0u;
  float u = fmaf(v, 2.5f, 5.5f);
  if (u >= 0.0f && u < 11.0f) {
    float tf = floorf(u);
    float f = u - tf, f2 = f * f, f3 = f2 * f, om = 1.0f - f;
    const float c6 = 1.0f / 6.0f;
    float w0 = om * om * om * c6;
    float w1 = (3.0f * f3 - 6.0f * f2 + 4.0f) * c6;
    float w2 = (-3.0f * f3 + 3.0f * f2 + 3.0f * f + 1.0f) * c6;
    float w3 = f3 * c6;
    unsigned long long w01 =
        (unsigned long long)f2h_bits(w0) |
        ((unsigned long long)f2h_bits(w1) << 16) |
        ((unsigned long long)f2h_bits(w2) << 32) |
        ((unsigned long long)f2h_bits(w3) << 48);
    int t = (int)tf;                 // 0..10; window starts at slot t-3
    int s = 16 * t - 48;             // bit shift into 128-bit field
    unsigned long long lo, hi;
    if (s >= 0) {
      lo = (s < 64) ? (w01 << s) : 0ull;
      hi = (s == 0) ? 0ull : ((s < 64) ? (w01 >> (64 - s)) : (w01 << (s - 64)));
    } else {
      lo = w01 >> (-s);
      hi = 0ull;
    }
    bs.x = (unsigned int)lo; bs.y = (unsigned int)(lo >> 32);
    bs.z = (unsigned int)hi; bs.w = (unsigned int)(hi >> 32);
  }
}

// KAN 3x3-conv accumulation, one position per lane, NO output channels.
// Weights (wS/wB) are og-contiguous global arrays laid out [cky][kx][j] ->
// one wide s_load per cky row -> SGPR operands. Plain loop (no prefetch),
// incremental addressing (no divisions).
template <int NO, int CHS, int ROWW>
__device__ __forceinline__ void kconv_plain(
    const uint4* bas, const unsigned short* slu,
    const uint4* __restrict__ wS, const float* __restrict__ wB,
    int y0, int x0, float (&acc)[NO]) {
  const uint4* wp = wS;
  const float* bp = wB;
  int baC = y0 * ROWW + x0;
  #pragma unroll 1
  for (int c = 0; c < 5; ++c) {
    int ba = baC;
    #pragma unroll 1
    for (int ky = 0; ky < 3; ++ky) {
      uint4 q0 = bas[ba], q1 = bas[ba + 1], q2 = bas[ba + 2];
      float s0 = h2f(slu[ba]), s1 = h2f(slu[ba + 1]), s2 = h2f(slu[ba + 2]);
      #pragma unroll
      for (int kx = 0; kx < 3; ++kx) {
        uint4 q = (kx == 0) ? q0 : ((kx == 1) ? q1 : q2);
        float sl = (kx == 0) ? s0 : ((kx == 1) ? s1 : s2);
        h2 a0 = u2h(q.x), a1 = u2h(q.y), a2 = u2h(q.z), a3 = u2h(q.w);
        #pragma unroll
        for (int j = 0; j < NO; ++j) {
          uint4 w = wp[kx * NO + j];
          float a = acc[j];
          a = fdot2(a0, u2h(w.x), a);
          a = fdot2(a1, u2h(w.y), a);
          a = fdot2(a2, u2h(w.z), a);
          a = fdot2(a3, u2h(w.w), a);
          acc[j] = fmaf(sl, bp[kx * NO + j], a);
        }
      }
      wp += 3 * NO; bp += 3 * NO;
      ba += ROWW;
    }
    baC += CHS;
  }
}

// ---------------- prep: conv weights (og-packed) + W1p4 + padded W2 ---------
__global__ __launch_bounds__(256) void k_prep(
    const float* __restrict__ bw1, const float* __restrict__ sw1,
    const float* __restrict__ bw2, const float* __restrict__ sw2,
    const float* __restrict__ bw3, const float* __restrict__ sw3,
    const float* __restrict__ w1, const float* __restrict__ w2,
    unsigned int* __restrict__ V1s, float* __restrict__ V1b,
    unsigned int* __restrict__ V2G0s, float* __restrict__ V2G0b,
    unsigned int* __restrict__ V2G1s, float* __restrict__ V2G1b,
    unsigned int* __restrict__ V3Gs, float* __restrict__ V3Gb,
    unsigned int* __restrict__ W1p4, float* __restrict__ W2p) {
  int t = blockIdx.x * 256 + threadIdx.x;
  if (t < 180) {  // L1: 9 taps x 5 outs x 4 pairs (tap-major, o contiguous)
    int p = t & 3, o = (t >> 2) % 5, in = t / 20;
    V1s[t] = pack2h(sw1[(o * 9 + in) * 8 + 2 * p], sw1[(o * 9 + in) * 8 + 2 * p + 1]);
  }
  if (t < 45)  { int o = t % 5, in = t / 5; V1b[t] = bw1[o * 9 + in]; }
  // L2 og0 (ch 0..2): [cky][kx][j<3] uint4 -> 540 words
  if (t < 540) {
    int p = t & 3, u4 = t >> 2;
    int j = u4 % 3, kx = (u4 / 3) % 3, cky = u4 / 9;
    int in = (cky / 3) * 9 + (cky % 3) * 3 + kx;
    V2G0s[t] = pack2h(sw2[(j * 45 + in) * 8 + 2 * p], sw2[(j * 45 + in) * 8 + 2 * p + 1]);
  }
  if (t < 135) {  // og0 biases
    int j = t % 3, kx = (t / 3) % 3, cky = t / 9;
    int in = (cky / 3) * 9 + (cky % 3) * 3 + kx;
    V2G0b[t] = bw2[j * 45 + in];
  }
  // L2 og1 (ch 3..4): [cky][kx][j<2] uint4 -> 360 words
  if (t < 360) {
    int p = t & 3, u4 = t >> 2;
    int j = u4 % 2, kx = (u4 / 2) % 3, cky = u4 / 6;
    int o = 3 + j;
    int in = (cky / 3) * 9 + (cky % 3) * 3 + kx;
    V2G1s[t] = pack2h(sw2[(o * 45 + in) * 8 + 2 * p], sw2[(o * 45 + in) * 8 + 2 * p + 1]);
  }
  if (t < 90) {   // og1 biases
    int j = t % 2, kx = (t / 2) % 3, cky = t / 6;
    int o = 3 + j;
    int in = (cky / 3) * 9 + (cky % 3) * 3 + kx;
    V2G1b[t] = bw2[o * 45 + in];
  }
  // L3: [ou][cky][kx] uint4 -> 360 words
  if (t < 360) {
    int p = t & 3, u4 = t >> 2;
    int kx = u4 % 3, cky = (u4 / 3) % 15, ou = u4 / 45;
    int in = (cky / 3) * 9 + (cky % 3) * 3 + kx;
    V3Gs[t] = pack2h(sw3[(ou * 45 + in) * 8 + 2 * p], sw3[(ou * 45 + in) * 8 + 2 * p + 1]);
  }
  if (t < 90) {
    int kx = t % 3, cky = (t / 3) % 15, ou = t / 45;
    int in = (cky / 3) * 9 + (cky % 3) * 3 + kx;
    V3Gb[t] = bw3[ou * 45 + in];
  }
  if (t < 43008) {  // W1p4[((g*512)+o)*4+j]: j-th k-pair of group g, out o
    int j = t & 3, o = (t >> 2) & 511, g = t >> 11;
    int kp = g * 4 + j;
    W1p4[t] = (o < 500 && kp < 81)
                  ? pack2h(w1[o * 162 + 2 * kp], w1[o * 162 + 2 * kp + 1])
                  : 0u;
  }
  if (t < 5120) {   // W2p[10][512] zero-padded
    int o = t >> 9, k = t & 511;
    W2p[t] = (k < 500) ? w2[o * 500 + k] : 0.0f;
  }
}

// ---------------- the fused per-image kernel (four waves per block) ---------
__global__ __launch_bounds__(256, 8) void k_fused(
    const float* __restrict__ x,
    const unsigned int* __restrict__ V1s, const float* __restrict__ V1b,
    const unsigned int* __restrict__ V2G0s, const float* __restrict__ V2G0b,
    const unsigned int* __restrict__ V2G1s, const float* __restrict__ V2G1b,
    const unsigned int* __restrict__ V3Gs, const float* __restrict__ V3Gb,
    const unsigned int* __restrict__ W1p4, const float* __restrict__ W2p,
    const float* __restrict__ b1, const float* __restrict__ b2,
    float* __restrict__ out) {
  __shared__ uint4 bas[845];               // 13,520 B
  __shared__ unsigned short slu16[848];    //  1,696 B
  __shared__ float red[40];                // fc2 cross-wave scratch
  float*        basF = (float*)bas;        // dword view of bas
  float*        h3f  = basF + 2048;        // h3 (162 f), dead-by-order region
  unsigned int* hpk  = (unsigned int*)basF + 2560;  // 84 uints
  const int b = blockIdx.x;
  const int tid = threadIdx.x;             // 0..255, four waves

  // P1: featurize input image (784 px)
  #pragma unroll 1
  for (int l = tid; l < 784; l += 256) {
    uint4 bs; float sl;
    featurize_regs(x[b * 784 + l], bs, sl);
    bas[l] = bs; slu16[l] = f2h_bits(sl);
  }
  __syncthreads();

  // P2: conv1 (1->5) + 2x2 maxpool; one pooled output per lane (tid<169).
  // TAP-OUTER: per (ky,kx): one contiguous SMEM weight row (20+5 dwords) +
  // 8 LDS reads, then 100 straight VALU ops. Window (dy,dx) gets tap (ky,kx)
  // applied to pixel (r0+dy+ky, c0+dx+kx).
  float h1v[5];
  if (tid < 169) {
    int py = tid / 13, px = tid % 13;
    int rowbase = (py * 2) * 28 + px * 2;
    float wacc[4][5];
    #pragma unroll
    for (int wi = 0; wi < 4; ++wi)
      #pragma unroll
      for (int o = 0; o < 5; ++o) wacc[wi][o] = 0.0f;
    const unsigned int* wp = V1s;
    const float* bp = V1b;
    int ba = rowbase;                      // tap (0,0)
    #pragma unroll 1
    for (int ky = 0; ky < 3; ++ky) {
      #pragma unroll 1
      for (int kx = 0; kx < 3; ++kx) {
        uint4 q00 = bas[ba],      q01 = bas[ba + 1];
        uint4 q10 = bas[ba + 28], q11 = bas[ba + 29];
        float s00 = h2f(slu16[ba]),      s01 = h2f(slu16[ba + 1]);
        float s10 = h2f(slu16[ba + 28]), s11 = h2f(slu16[ba + 29]);
        #pragma unroll
        for (int dy = 0; dy < 2; ++dy) {
          #pragma unroll
          for (int dx = 0; dx < 2; ++dx) {
            uint4 q  = dy ? (dx ? q11 : q10) : (dx ? q01 : q00);
            float sl = dy ? (dx ? s11 : s10) : (dx ? s01 : s00);
            h2 a0 = u2h(q.x), a1 = u2h(q.y), a2 = u2h(q.z), a3 = u2h(q.w);
            #pragma unroll
            for (int o = 0; o < 5; ++o) {
              float a = wacc[dy * 2 + dx][o];
              a = fdot2(a0, u2h(wp[o * 4 + 0]), a);
              a = fdot2(a1, u2h(wp[o * 4 + 1]), a);
              a = fdot2(a2, u2h(wp[o * 4 + 2]), a);
              a = fdot2(a3, u2h(wp[o * 4 + 3]), a);
              wacc[dy * 2 + dx][o] = fmaf(sl, bp[o], a);
            }
          }
        }
        wp += 20; bp += 5;
        ba += 1;                           // next kx
      }
      ba += 25;                            // (ky+1)*28 from ky*28+3
    }
    #pragma unroll
    for (int o = 0; o < 5; ++o)
      h1v[o] = fmaxf(fmaxf(wacc[0][o], wacc[1][o]),
                     fmaxf(wacc[2][o], wacc[3][o]));
  }
  __syncthreads();  // all conv1 LDS reads (all waves) done
  // write featurized h1 (aliases the input-pixel region)
  if (tid < 169) {
    #pragma unroll
    for (int o = 0; o < 5; ++o) {
      uint4 bs; float sl;
      featurize_regs(h1v[o], bs, sl);
      bas[o * 169 + tid] = bs; slu16[o * 169 + tid] = f2h_bits(sl);
    }
  }
  __syncthreads();

  // P4: conv2 (5->5); lanes split by (position, channel-group):
  //   og=0 (waves 0,1): channels 0..2   og=1 (waves 2,3): channels 3..4
  int og = __builtin_amdgcn_readfirstlane(tid >> 7);   // wave-uniform
  int p2 = tid & 127;
  float acc2a[3] = {0.0f, 0.0f, 0.0f};
  float acc2b[2] = {0.0f, 0.0f};
  {
    int pc = (p2 < 121) ? p2 : 120;     // clamp (writeback guarded)
    int y0 = pc / 11, x0 = pc % 11;
    if (og == 0)
      kconv_plain<3, 169, 13>(bas, slu16, (const uint4*)V2G0s, V2G0b, y0, x0, acc2a);
    else
      kconv_plain<2, 169, 13>(bas, slu16, (const uint4*)V2G1s, V2G1b, y0, x0, acc2b);
  }
  __syncthreads();  // all conv2 reads done before h2 overwrites bas
  if (p2 < 121) {
    if (og == 0) {
      #pragma unroll
      for (int j = 0; j < 3; ++j) {
        uint4 bs; float sl;
        featurize_regs(acc2a[j], bs, sl);
        bas[j * 121 + p2] = bs; slu16[j * 121 + p2] = f2h_bits(sl);
      }
    } else {
      #pragma unroll
      for (int j = 0; j < 2; ++j) {
        uint4 bs; float sl;
        featurize_regs(acc2b[j], bs, sl);
        bas[(3 + j) * 121 + p2] = bs; slu16[(3 + j) * 121 + p2] = f2h_bits(sl);
      }
    }
  }
  __syncthreads();

  // P6: conv3 (5->2); lanes split by (position, output):
  //   waves 0,1: out 0   waves 2,3: out 1
  float acc3[1] = {0.0f};
  {
    int pc = (p2 < 81) ? p2 : 80;
    int y0 = pc / 9, x0 = pc % 9;
    kconv_plain<1, 121, 11>(bas, slu16, (const uint4*)V3Gs + og * 45,
                            V3Gb + og * 45, y0, x0, acc3);
  }
  __syncthreads();  // all conv3 reads done before h3 overwrites bas region
  if (p2 < 81) h3f[og * 81 + p2] = acc3[0];
  __syncthreads();
  if (tid < 84)
    hpk[tid] = (tid < 81) ? pack2h(h3f[2 * tid], h3f[2 * tid + 1]) : 0u;
  __syncthreads();

  // P7: fc1 (162->500) + bias + ReLU; 2 outs/lane; double-buffered global
  // loads (vmcnt is in-order & separate from LDS lgkmcnt -> real prefetch).
  float fa[2] = {0.0f, 0.0f};
  {
    const uint4* hp4 = (const uint4*)hpk;
    const uint4* wbase = (const uint4*)W1p4 + tid;
    uint4 wA[2], wB[2];
    #pragma unroll
    for (int i = 0; i < 2; ++i) wA[i] = wbase[i * 256];   // group 0
    #pragma unroll 1
    for (int g = 0; g < 21; g += 2) {
      if (g + 1 < 21) {
        const uint4* p = wbase + (g + 1) * 512;
        #pragma unroll
        for (int i = 0; i < 2; ++i) wB[i] = p[i * 256];
      }
      {
        uint4 hk = hp4[g];
        #pragma unroll
        for (int i = 0; i < 2; ++i) {
          float a = fa[i];
          a = fdot2(u2h(hk.x), u2h(wA[i].x), a);
          a = fdot2(u2h(hk.y), u2h(wA[i].y), a);
          a = fdot2(u2h(hk.z), u2h(wA[i].z), a);
          a = fdot2(u2h(hk.w), u2h(wA[i].w), a);
          fa[i] = a;
        }
      }
      if (g + 2 < 21) {
        const uint4* p = wbase + (g + 2) * 512;
        #pragma unroll
        for (int i = 0; i < 2; ++i) wA[i] = p[i * 256];
      }
      if (g + 1 < 21) {
        uint4 hk = hp4[g + 1];
        #pragma unroll
        for (int i = 0; i < 2; ++i) {
          float a = fa[i];
          a = fdot2(u2h(hk.x), u2h(wB[i].x), a);
          a = fdot2(u2h(hk.y), u2h(wB[i].y), a);
          a = fdot2(u2h(hk.z), u2h(wB[i].z), a);
          a = fdot2(u2h(hk.w), u2h(wB[i].w), a);
          fa[i] = a;
        }
      }
    }
  }
  #pragma unroll
  for (int i = 0; i < 2; ++i) {
    int o = tid + 256 * i;
    float bb = (o < 500) ? b1[o] : 0.0f;
    float v = fa[i] + bb;
    basF[o] = (v > 0.0f && o < 500) ? v : 0.0f;  // fc1out[512] in bas[0..127]
  }
  __syncthreads();

  // P8: fc2 (500->10): lane covers k = 2*tid..2*tid+1, shfl + LDS reduction
  float acc10[10];
  {
    float2 ha = ((const float2*)basF)[tid];
    #pragma unroll
    for (int o = 0; o < 10; ++o) {
      float2 w = ((const float2*)&W2p[o * 512])[tid];
      acc10[o] = ha.x * w.x + ha.y * w.y;
    }
  }
  #pragma unroll
  for (int off = 32; off > 0; off >>= 1) {
    #pragma unroll
    for (int o = 0; o < 10; ++o) acc10[o] += __shfl_down(acc10[o], off);
  }
  if ((tid & 63) == 0) {
    int wid = tid >> 6;
    #pragma unroll
    for (int o = 0; o < 10; ++o) red[wid * 10 + o] = acc10[o];
  }
  __syncthreads();
  if (tid < 10)
    out[b * 10 + tid] = red[tid] + red[10 + tid] + red[20 + tid] + red[30 + tid] + b2[tid];
}

// ---------------------------------------------------------------------------
extern "C" void kernel_launch(void* const* d_in, const int* in_sizes, int n_in,
                              void* d_out, int out_size, void* d_ws, size_t ws_size,
                              hipStream_t stream) {
  (void)in_sizes; (void)n_in; (void)out_size; (void)ws_size;
  const float* x   = (const float*)d_in[0];
  const float* bw1 = (const float*)d_in[1];
  const float* sw1 = (const float*)d_in[2];
  const float* bw2 = (const float*)d_in[3];
  const float* sw2 = (const float*)d_in[4];
  const float* bw3 = (const float*)d_in[5];
  const float* sw3 = (const float*)d_in[6];
  const float* w1  = (const float*)d_in[7];
  const float* b1  = (const float*)d_in[8];
  const float* w2  = (const float*)d_in[9];
  const float* b2  = (const float*)d_in[10];
  float* out = (float*)d_out;

  char* ws = (char*)d_ws;
  unsigned int* V1s   = (unsigned int*)(ws);           // 180 u   (720 B)
  float*        V1b   = (float*)(ws + 768);            // 45 f    (180 B)
  unsigned int* V2G0s = (unsigned int*)(ws + 1024);    // 540 u   (2,160 B)
  unsigned int* V2G1s = (unsigned int*)(ws + 3200);    // 360 u   (1,440 B)
  unsigned int* V3Gs  = (unsigned int*)(ws + 4640);    // 360 u   (1,440 B)
  float*        V2G0b = (float*)(ws + 6080);           // 135 f   (540 B)
  float*        V2G1b = (float*)(ws + 6624);           // 90 f    (360 B)
  float*        V3Gb  = (float*)(ws + 6984);           // 90 f    (360 B)
  float*        W2p   = (float*)(ws + 7680);           // 5,120 f (20,480 B)
  unsigned int* W1p4  = (unsigned int*)(ws + 28672);   // 43,008 u (172,032 B)

  k_prep<<<168, 256, 0, stream>>>(bw1, sw1, bw2, sw2, bw3, sw3, w1, w2,
                                  V1s, V1b, V2G0s, V2G0b, V2G1s, V2G1b,
                                  V3Gs, V3Gb, W1p4, W2p);
  k_fused<<<2048, 256, 0, stream>>>(x, V1s, V1b, V2G0s, V2G0b, V2G1s, V2G1b,
                                    V3Gs, V3Gb, W1p4, W2p, b1, b2, out);
}